// Round 8
// baseline (850.026 us; speedup 1.0000x reference)
//
#include <hip/hip_runtime.h>
#include <hip/hip_fp16.h>

#define TOTAL_NODES 150000
#define EMBED_DIM   128
#define NUM_EDGES   2000000
#define N_ELEM      (TOTAL_NODES * EMBED_DIM)   // 19,200,000

#define BS_NODES    64                           // nodes per bucket
#define NB          2344                         // ceil(150000/64)
#define NS          64                           // shards (XCD = shard&7 under round-robin)
#define NREG        (NB * NS)                    // 150016 regions
#define SCAP        80                           // per-region cap (mean 40, +6.3 sigma)
#define MAXE        3072                         // max edges per bucket (mean 2560, max ~2790)
#define PBLK        2048                         // blocks per relation in place (1954 active)

typedef float vf2 __attribute__((ext_vector_type(2)));
typedef float vf4 __attribute__((ext_vector_type(4)));

// fp32 -> fp16 table conversion (embh lives in d_out scratch) + cursor zeroing
__global__ void convert_kernel(const float* __restrict__ in, __half* __restrict__ outh,
                               int* __restrict__ cursor) {
    const int n4 = N_ELEM / 4;
    const int stride = gridDim.x * blockDim.x;
    const int gid = blockIdx.x * blockDim.x + threadIdx.x;
    for (int i = gid; i < NREG; i += stride) cursor[i] = 0;
    for (int i = gid; i < n4; i += stride) {
        float4 v = reinterpret_cast<const float4*>(in)[i];
        union { __half2 h[2]; vf2 f; } u;
        u.h[0] = __float22half2_rn({v.x, v.y});
        u.h[1] = __float22half2_rn({v.z, v.w});
        __builtin_nontemporal_store(u.f, reinterpret_cast<vf2*>(outh) + i);
    }
}

// all 3 relations in one launch; int4-vectorized edge reads
__global__ void place_all(const int* __restrict__ s0, const int* __restrict__ d0,
                          const int* __restrict__ s1, const int* __restrict__ d1,
                          const int* __restrict__ s2, const int* __restrict__ d2,
                          int* __restrict__ cursor, unsigned int* __restrict__ buf) {
    const unsigned int rel = blockIdx.x >> 11;        // 0,1,2
    const int inner = blockIdx.x & (PBLK - 1);
    const int shard = blockIdx.x & (NS - 1);
    const int base = (inner * 256 + threadIdx.x) * 4;
    if (base + 4 > NUM_EDGES) return;                 // NUM_EDGES % 4 == 0
    const int* sp = (rel == 0) ? s0 : ((rel == 1) ? s1 : s2);
    const int* dp = (rel == 0) ? d0 : ((rel == 1) ? d1 : d2);
    const int4 s4 = *reinterpret_cast<const int4*>(sp + base);
    const int4 d4 = *reinterpret_cast<const int4*>(dp + base);
    {
        const int reg = shard * NB + (s4.x >> 6);
        const int pos = atomicAdd(&cursor[reg], 1);
        if (pos < SCAP) buf[(size_t)reg * SCAP + pos] =
            ((unsigned int)(s4.x & 63) << 20) | ((unsigned int)d4.x << 2) | rel;
    }
    {
        const int reg = shard * NB + (s4.y >> 6);
        const int pos = atomicAdd(&cursor[reg], 1);
        if (pos < SCAP) buf[(size_t)reg * SCAP + pos] =
            ((unsigned int)(s4.y & 63) << 20) | ((unsigned int)d4.y << 2) | rel;
    }
    {
        const int reg = shard * NB + (s4.z >> 6);
        const int pos = atomicAdd(&cursor[reg], 1);
        if (pos < SCAP) buf[(size_t)reg * SCAP + pos] =
            ((unsigned int)(s4.z & 63) << 20) | ((unsigned int)d4.z << 2) | rel;
    }
    {
        const int reg = shard * NB + (s4.w >> 6);
        const int pos = atomicAdd(&cursor[reg], 1);
        if (pos < SCAP) buf[(size_t)reg * SCAP + pos] =
            ((unsigned int)(s4.w & 63) << 20) | ((unsigned int)d4.w << 2) | rel;
    }
}

// per-bucket LDS counting sort + fp16 gather accumulate, 8x unrolled gather
// MODE 0: aggh[n] = raw1 (fp16)
// MODE 1: out[n]  = embf[n]/3 + aggh_row/9 + raw2/27   (fp32)
template <int MODE>
__global__ __launch_bounds__(256) void pull_kernel(const __half* __restrict__ xh,
                                                   const int* __restrict__ cnts,
                                                   const unsigned int* __restrict__ buf,
                                                   const float* __restrict__ embf,
                                                   __half* __restrict__ aggh,
                                                   float* __restrict__ outf) {
    __shared__ unsigned int sorted[MAXE];
    __shared__ int scnt[NS];
    __shared__ int spre[NS + 1];
    __shared__ int cnt[BS_NODES];
    __shared__ int cur[BS_NODES];
    __shared__ int noff[BS_NODES + 1];
    const int b = blockIdx.x, t = threadIdx.x;

    // prefetch shard counts (one coalesced-ish pass, no dependent scalar loads later)
    if (t < NS) scnt[t] = min(cnts[t * NB + b], SCAP);
    if (t < BS_NODES) cnt[t] = 0;
    __syncthreads();
    // inclusive scan over NS shard counts -> spre (exclusive form)
    if (t < NS) spre[t + 1] = scnt[t];
    if (t == 0) spre[0] = 0;
    __syncthreads();
    for (int d = 1; d < NS; d <<= 1) {
        int v = 0;
        if (t >= d && t < NS) v = spre[t + 1 - d];
        __syncthreads();
        if (t >= d && t < NS) spre[t + 1] += v;
        __syncthreads();
    }
    const int ne = spre[NS];

    // pass 1: per-node histogram (flattened over all shard regions)
    for (int j = t; j < ne; j += 256) {
        int sh = 0;
        #pragma unroll
        for (int s = 32; s > 0; s >>= 1)
            if (sh + s < NS + 1 && spre[sh + s] <= j) sh += s;
        const unsigned int p = buf[(size_t)(sh * NB + b) * SCAP + (j - spre[sh])];
        atomicAdd(&cnt[p >> 20], 1);
    }
    __syncthreads();
    // inclusive scan over 64 node counts
    for (int d = 1; d < BS_NODES; d <<= 1) {
        int v = 0;
        if (t >= d && t < BS_NODES) v = cnt[t - d];
        __syncthreads();
        if (t >= d && t < BS_NODES) cnt[t] += v;
        __syncthreads();
    }
    if (t == 0) noff[0] = 0;
    if (t < BS_NODES) { noff[t + 1] = cnt[t]; cur[t] = (t == 0) ? 0 : cnt[t - 1]; }
    __syncthreads();
    // pass 2: place into sorted[]
    for (int j = t; j < ne; j += 256) {
        int sh = 0;
        #pragma unroll
        for (int s = 32; s > 0; s >>= 1)
            if (sh + s < NS + 1 && spre[sh + s] <= j) sh += s;
        const unsigned int p = buf[(size_t)(sh * NB + b) * SCAP + (j - spre[sh])];
        int pos = atomicAdd(&cur[p >> 20], 1);
        sorted[pos] = p & 0xFFFFFu;           // (dst<<2)|rel
    }
    __syncthreads();

    const int hw = t >> 5, lane = t & 31;
    const char* xb = reinterpret_cast<const char*>(xh) + (lane << 3);
    union F2H { vf2 f; __half2 h[2]; };
    for (int ln = hw; ln < BS_NODES; ln += 8) {
        const int node = b * BS_NODES + ln;
        if (node >= TOTAL_NODES) break;
        vf4 acc0 = {0.f, 0.f, 0.f, 0.f};
        vf4 acc1 = {0.f, 0.f, 0.f, 0.f};
        int i = noff[ln];
        const int e1 = noff[ln + 1];
        for (; i + 8 <= e1; i += 8) {
            const unsigned int p0 = sorted[i + 0], p1 = sorted[i + 1];
            const unsigned int p2 = sorted[i + 2], p3 = sorted[i + 3];
            const unsigned int p4 = sorted[i + 4], p5 = sorted[i + 5];
            const unsigned int p6 = sorted[i + 6], p7 = sorted[i + 7];
            F2H u0, u1, u2, u3, u4, u5, u6, u7;
            u0.f = *reinterpret_cast<const vf2*>(xb + ((size_t)(p0 >> 2) << 8));
            u1.f = *reinterpret_cast<const vf2*>(xb + ((size_t)(p1 >> 2) << 8));
            u2.f = *reinterpret_cast<const vf2*>(xb + ((size_t)(p2 >> 2) << 8));
            u3.f = *reinterpret_cast<const vf2*>(xb + ((size_t)(p3 >> 2) << 8));
            u4.f = *reinterpret_cast<const vf2*>(xb + ((size_t)(p4 >> 2) << 8));
            u5.f = *reinterpret_cast<const vf2*>(xb + ((size_t)(p5 >> 2) << 8));
            u6.f = *reinterpret_cast<const vf2*>(xb + ((size_t)(p6 >> 2) << 8));
            u7.f = *reinterpret_cast<const vf2*>(xb + ((size_t)(p7 >> 2) << 8));
            const float w0 = ((p0 & 3u) == 1u) ? 0.5f : (((p0 & 3u) == 2u) ? 2.0f : 1.0f);
            const float w1 = ((p1 & 3u) == 1u) ? 0.5f : (((p1 & 3u) == 2u) ? 2.0f : 1.0f);
            const float w2 = ((p2 & 3u) == 1u) ? 0.5f : (((p2 & 3u) == 2u) ? 2.0f : 1.0f);
            const float w3 = ((p3 & 3u) == 1u) ? 0.5f : (((p3 & 3u) == 2u) ? 2.0f : 1.0f);
            const float w4 = ((p4 & 3u) == 1u) ? 0.5f : (((p4 & 3u) == 2u) ? 2.0f : 1.0f);
            const float w5 = ((p5 & 3u) == 1u) ? 0.5f : (((p5 & 3u) == 2u) ? 2.0f : 1.0f);
            const float w6 = ((p6 & 3u) == 1u) ? 0.5f : (((p6 & 3u) == 2u) ? 2.0f : 1.0f);
            const float w7 = ((p7 & 3u) == 1u) ? 0.5f : (((p7 & 3u) == 2u) ? 2.0f : 1.0f);
            float2 f0a = __half22float2(u0.h[0]), f0b = __half22float2(u0.h[1]);
            float2 f1a = __half22float2(u1.h[0]), f1b = __half22float2(u1.h[1]);
            float2 f2a = __half22float2(u2.h[0]), f2b = __half22float2(u2.h[1]);
            float2 f3a = __half22float2(u3.h[0]), f3b = __half22float2(u3.h[1]);
            float2 f4a = __half22float2(u4.h[0]), f4b = __half22float2(u4.h[1]);
            float2 f5a = __half22float2(u5.h[0]), f5b = __half22float2(u5.h[1]);
            float2 f6a = __half22float2(u6.h[0]), f6b = __half22float2(u6.h[1]);
            float2 f7a = __half22float2(u7.h[0]), f7b = __half22float2(u7.h[1]);
            acc0.x = fmaf(w0, f0a.x, acc0.x); acc0.y = fmaf(w0, f0a.y, acc0.y);
            acc0.z = fmaf(w0, f0b.x, acc0.z); acc0.w = fmaf(w0, f0b.y, acc0.w);
            acc1.x = fmaf(w1, f1a.x, acc1.x); acc1.y = fmaf(w1, f1a.y, acc1.y);
            acc1.z = fmaf(w1, f1b.x, acc1.z); acc1.w = fmaf(w1, f1b.y, acc1.w);
            acc0.x = fmaf(w2, f2a.x, acc0.x); acc0.y = fmaf(w2, f2a.y, acc0.y);
            acc0.z = fmaf(w2, f2b.x, acc0.z); acc0.w = fmaf(w2, f2b.y, acc0.w);
            acc1.x = fmaf(w3, f3a.x, acc1.x); acc1.y = fmaf(w3, f3a.y, acc1.y);
            acc1.z = fmaf(w3, f3b.x, acc1.z); acc1.w = fmaf(w3, f3b.y, acc1.w);
            acc0.x = fmaf(w4, f4a.x, acc0.x); acc0.y = fmaf(w4, f4a.y, acc0.y);
            acc0.z = fmaf(w4, f4b.x, acc0.z); acc0.w = fmaf(w4, f4b.y, acc0.w);
            acc1.x = fmaf(w5, f5a.x, acc1.x); acc1.y = fmaf(w5, f5a.y, acc1.y);
            acc1.z = fmaf(w5, f5b.x, acc1.z); acc1.w = fmaf(w5, f5b.y, acc1.w);
            acc0.x = fmaf(w6, f6a.x, acc0.x); acc0.y = fmaf(w6, f6a.y, acc0.y);
            acc0.z = fmaf(w6, f6b.x, acc0.z); acc0.w = fmaf(w6, f6b.y, acc0.w);
            acc1.x = fmaf(w7, f7a.x, acc1.x); acc1.y = fmaf(w7, f7a.y, acc1.y);
            acc1.z = fmaf(w7, f7b.x, acc1.z); acc1.w = fmaf(w7, f7b.y, acc1.w);
        }
        for (; i < e1; ++i) {
            const unsigned int p = sorted[i];
            const float w = ((p & 3u) == 1u) ? 0.5f : (((p & 3u) == 2u) ? 2.0f : 1.0f);
            F2H u;
            u.f = *reinterpret_cast<const vf2*>(xb + ((size_t)(p >> 2) << 8));
            float2 fa = __half22float2(u.h[0]), fb = __half22float2(u.h[1]);
            acc0.x = fmaf(w, fa.x, acc0.x); acc0.y = fmaf(w, fa.y, acc0.y);
            acc0.z = fmaf(w, fb.x, acc0.z); acc0.w = fmaf(w, fb.y, acc0.w);
        }
        vf4 acc = acc0 + acc1;
        if (MODE == 0) {
            F2H o;
            o.h[0] = __float22half2_rn({acc.x, acc.y});
            o.h[1] = __float22half2_rn({acc.z, acc.w});
            __builtin_nontemporal_store(o.f,
                reinterpret_cast<vf2*>(reinterpret_cast<char*>(aggh) + (((size_t)node) << 8) + (lane << 3)));
        } else {
            const float4 e = *reinterpret_cast<const float4*>(embf + (size_t)node * EMBED_DIM + lane * 4);
            F2H a;
            a.f = *reinterpret_cast<const vf2*>(
                reinterpret_cast<const char*>(xh) + (((size_t)node) << 8) + (lane << 3));
            float2 a0 = __half22float2(a.h[0]);
            float2 a1 = __half22float2(a.h[1]);
            const float c1 = 1.f / 3.f, c2 = 1.f / 9.f, c3 = 1.f / 27.f;
            vf4 z;
            z.x = e.x * c1 + a0.x * c2 + acc.x * c3;
            z.y = e.y * c1 + a0.y * c2 + acc.y * c3;
            z.z = e.z * c1 + a1.x * c2 + acc.z * c3;
            z.w = e.w * c1 + a1.y * c2 + acc.w * c3;
            __builtin_nontemporal_store(z,
                reinterpret_cast<vf4*>(outf + (size_t)node * EMBED_DIM + lane * 4));
        }
    }
}

extern "C" void kernel_launch(void* const* d_in, const int* in_sizes, int n_in,
                              void* d_out, int out_size, void* d_ws, size_t ws_size,
                              hipStream_t stream) {
    const float* emb = (const float*)d_in[0];
    const int* s0 = (const int*)d_in[1];
    const int* d0 = (const int*)d_in[2];
    const int* s1 = (const int*)d_in[3];
    const int* d1 = (const int*)d_in[4];
    const int* s2 = (const int*)d_in[5];
    const int* d2 = (const int*)d_in[6];
    float* out = (float*)d_out;
    __half* embh = (__half*)d_out;               // d_out doubles as fp16-emb scratch

    // workspace (~87 MB)
    char* ws = (char*)d_ws;
    __half*       aggh   = (__half*)ws;          ws += (size_t)N_ELEM * 2;     // 38.4 MB
    int*          cursor = (int*)ws;             ws += (size_t)NREG * 4;       // 600 KB
    unsigned int* buf    = (unsigned int*)ws;                                  // 48.0 MB

    convert_kernel<<<2048, 256, 0, stream>>>(emb, embh, cursor);
    place_all<<<3 * PBLK, 256, 0, stream>>>(s0, d0, s1, d1, s2, d2, cursor, buf);

    // layer 1: aggh = raw1 (fp16)
    pull_kernel<0><<<NB, 256, 0, stream>>>(embh, cursor, buf, nullptr, aggh, nullptr);
    // layer 2 + combine: out = emb/3 + raw1/9 + raw2/27
    pull_kernel<1><<<NB, 256, 0, stream>>>(aggh, cursor, buf, emb, nullptr, out);
}

// Round 9
// 665.408 us; speedup vs baseline: 1.2775x; 1.2775x over previous
//
#include <hip/hip_runtime.h>
#include <hip/hip_fp16.h>

#define TOTAL_NODES 150000
#define EMBED_DIM   128
#define NUM_EDGES   2000000
#define N_ELEM      (TOTAL_NODES * EMBED_DIM)   // 19,200,000

#define NGRP     37          // coarse groups of 4096 nodes (src>>12)
#define GCAP     180224      // words per group region (44*4096; mean fill 162K, +45σ safe)
#define EPB1     4096        // edges per block in split kernels
#define NBKT     2344        // buckets of 64 nodes (src>>6)
#define NBKT_PAD 2368        // 37*64
#define SCAP2    2944        // per-bucket capacity (mean 2560, sigma ~51, +7.5σ)
#define P2BLK    44          // split2 blocks per group
#define BS_NODES 64

typedef float vf2 __attribute__((ext_vector_type(2)));
typedef float vf4 __attribute__((ext_vector_type(4)));

// fp32 -> fp16 table (embh lives in d_out scratch) + cursor zeroing
__global__ void convert_kernel(const float* __restrict__ in, __half* __restrict__ outh,
                               int* __restrict__ gcur, int* __restrict__ bcur) {
    const int n4 = N_ELEM / 4;
    const int stride = gridDim.x * blockDim.x;
    const int gid = blockIdx.x * blockDim.x + threadIdx.x;
    if (gid < NGRP) gcur[gid] = 0;
    if (gid < NBKT_PAD) bcur[gid] = 0;
    for (int i = gid; i < n4; i += stride) {
        float4 v = reinterpret_cast<const float4*>(in)[i];
        union { __half2 h[2]; vf2 f; } u;
        u.h[0] = __float22half2_rn({v.x, v.y});
        u.h[1] = __float22half2_rn({v.z, v.w});
        __builtin_nontemporal_store(u.f, reinterpret_cast<vf2*>(outh) + i);
    }
}

// pass 1: bin 6M edges into 37 coarse groups, contiguous coalesced runs per block
__global__ __launch_bounds__(256) void split1(const int* __restrict__ s0, const int* __restrict__ d0,
                                              const int* __restrict__ s1, const int* __restrict__ d1,
                                              const int* __restrict__ s2, const int* __restrict__ d2,
                                              int* __restrict__ gcur, unsigned int* __restrict__ gbuf) {
    const int rel   = blockIdx.x >> 9;               // 512 blocks per relation
    const int inner = blockIdx.x & 511;
    const int base  = inner * EPB1;
    const int ne    = min(EPB1, NUM_EDGES - base);
    if (ne <= 0) return;
    const int* sp = (rel == 0) ? s0 : ((rel == 1) ? s1 : s2);
    const int* dp = (rel == 0) ? d0 : ((rel == 1) ? d1 : d2);

    __shared__ int cnt[NGRP], excl[NGRP], bas[NGRP], rc[NGRP];
    __shared__ unsigned int stage[EPB1];
    __shared__ unsigned char grp[EPB1];
    const int t = threadIdx.x;
    for (int i = t; i < NGRP; i += 256) cnt[i] = 0;
    __syncthreads();

    unsigned int pay[16];
    int pg[16];
    #pragma unroll
    for (int q = 0; q < 4; ++q) {
        const int idx = (q * 256 + t) * 4;
        if (idx < ne) {                               // ne always multiple of 4
            const int4 s4 = *reinterpret_cast<const int4*>(sp + base + idx);
            const int4 d4 = *reinterpret_cast<const int4*>(dp + base + idx);
            const int ss[4] = {s4.x, s4.y, s4.z, s4.w};
            const int dd[4] = {d4.x, d4.y, d4.z, d4.w};
            #pragma unroll
            for (int k = 0; k < 4; ++k) {
                const int g = ss[k] >> 12;
                pay[q * 4 + k] = ((unsigned int)(ss[k] & 4095) << 20) |
                                 ((unsigned int)dd[k] << 2) | (unsigned int)rel;
                pg[q * 4 + k] = g;
                atomicAdd(&cnt[g], 1);
            }
        }
    }
    __syncthreads();
    if (t == 0) { int run = 0; for (int i = 0; i < NGRP; ++i) { excl[i] = run; run += cnt[i]; } }
    __syncthreads();
    if (t < NGRP) { if (cnt[t] > 0) bas[t] = atomicAdd(&gcur[t], cnt[t]); rc[t] = excl[t]; }
    __syncthreads();
    #pragma unroll
    for (int q = 0; q < 4; ++q) {
        const int idx = (q * 256 + t) * 4;
        if (idx < ne) {
            #pragma unroll
            for (int k = 0; k < 4; ++k) {
                const int g = pg[q * 4 + k];
                const int pos = atomicAdd(&rc[g], 1);
                stage[pos] = pay[q * 4 + k];
                grp[pos] = (unsigned char)g;
            }
        }
    }
    __syncthreads();
    for (int j = t; j < ne; j += 256) {
        const int g = grp[j];
        const int o = bas[g] + (j - excl[g]);
        if (o < GCAP) gbuf[(size_t)g * GCAP + o] = stage[j];
    }
}

// pass 2: split each group into its 64 buckets (contiguous bucket regions)
__global__ __launch_bounds__(256) void split2(const int* __restrict__ gcur,
                                              const unsigned int* __restrict__ gbuf,
                                              int* __restrict__ bcur, unsigned int* __restrict__ buf2) {
    const int g     = blockIdx.x / P2BLK;
    const int inner = blockIdx.x % P2BLK;
    const int gsz   = min(gcur[g], GCAP);
    const int base  = inner * EPB1;
    if (base >= gsz) return;
    const int ne = min(EPB1, gsz - base);
    const unsigned int* src = gbuf + (size_t)g * GCAP + base;

    __shared__ int cnt[64], excl[64], bas2[64], rc[64];
    __shared__ unsigned int stage[EPB1];
    const int t = threadIdx.x;
    if (t < 64) cnt[t] = 0;
    __syncthreads();

    unsigned int pay[16];
    #pragma unroll
    for (int q = 0; q < 4; ++q) {
        const int idx = (q * 256 + t) * 4;
        if (idx + 4 <= ne) {
            const uint4 v = *reinterpret_cast<const uint4*>(src + idx);
            pay[q * 4 + 0] = v.x; pay[q * 4 + 1] = v.y;
            pay[q * 4 + 2] = v.z; pay[q * 4 + 3] = v.w;
            atomicAdd(&cnt[(v.x >> 26) & 63], 1);
            atomicAdd(&cnt[(v.y >> 26) & 63], 1);
            atomicAdd(&cnt[(v.z >> 26) & 63], 1);
            atomicAdd(&cnt[(v.w >> 26) & 63], 1);
        } else {
            #pragma unroll
            for (int k = 0; k < 4; ++k) {
                if (idx + k < ne) {
                    const unsigned int p = src[idx + k];
                    pay[q * 4 + k] = p;
                    atomicAdd(&cnt[(p >> 26) & 63], 1);
                }
            }
        }
    }
    __syncthreads();
    if (t == 0) { int run = 0; for (int i = 0; i < 64; ++i) { excl[i] = run; run += cnt[i]; } }
    __syncthreads();
    if (t < 64) { if (cnt[t] > 0) bas2[t] = atomicAdd(&bcur[g * 64 + t], cnt[t]); rc[t] = excl[t]; }
    __syncthreads();
    #pragma unroll
    for (int q = 0; q < 4; ++q) {
        const int idx = (q * 256 + t) * 4;
        #pragma unroll
        for (int k = 0; k < 4; ++k) {
            if (idx + k < ne) {
                const unsigned int p = pay[q * 4 + k];
                const int pos = atomicAdd(&rc[(p >> 26) & 63], 1);
                stage[pos] = p;
            }
        }
    }
    __syncthreads();
    for (int j = t; j < ne; j += 256) {
        const unsigned int p = stage[j];
        const int bb = (p >> 26) & 63;
        const int o = bas2[bb] + (j - excl[bb]);
        if (o < SCAP2) buf2[(size_t)(g * 64 + bb) * SCAP2 + o] = p;
    }
}

// pull: per-bucket LDS counting sort + 16B/lane fp16 gather (2 edges per half-wave instr)
// MODE 0: aggh[n] = raw1 (fp16)
// MODE 1: out[n]  = embf[n]/3 + aggh_row/9 + raw2/27 (fp32)
template <int MODE>
__global__ __launch_bounds__(256) void pull_kernel(const __half* __restrict__ xh,
                                                   const int* __restrict__ bcur,
                                                   const unsigned int* __restrict__ buf2,
                                                   const float* __restrict__ embf,
                                                   __half* __restrict__ aggh,
                                                   float* __restrict__ outf) {
    __shared__ unsigned int sorted[SCAP2];
    __shared__ int cnt[64], cur[64], noff[65];
    const int b = blockIdx.x, t = threadIdx.x;
    const int c = min(bcur[b], SCAP2);
    const unsigned int* rb = buf2 + (size_t)b * SCAP2;
    if (t < 64) cnt[t] = 0;
    __syncthreads();
    for (int i = t; i < c; i += 256) atomicAdd(&cnt[(rb[i] >> 20) & 63], 1);
    __syncthreads();
    if (t == 0) { int run = 0; for (int i = 0; i < 64; ++i) { noff[i] = run; run += cnt[i]; } noff[64] = run; }
    __syncthreads();
    if (t < 64) cur[t] = noff[t];
    __syncthreads();
    for (int i = t; i < c; i += 256) {
        const unsigned int p = rb[i];
        const int pos = atomicAdd(&cur[(p >> 20) & 63], 1);
        sorted[pos] = p & 0xFFFFFu;                   // (dst<<2)|rel
    }
    __syncthreads();

    const int hw = t >> 5, lane = t & 31;
    const int sub = lane >> 4, ch = lane & 15;        // lane handles channels [8ch, 8ch+8)
    const char* xb = reinterpret_cast<const char*>(xh) + (ch << 4);
    union F4H { vf4 f; __half2 h[4]; };
    const float c1 = 1.f / 3.f, c2 = 1.f / 9.f, c3 = 1.f / 27.f;

#define EDGE_FMA(P, W, ACC0, ACC1) do {                                         \
        F4H _u; _u.f = *reinterpret_cast<const vf4*>(xb + ((size_t)((P) >> 2) << 8)); \
        float2 _x0 = __half22float2(_u.h[0]), _x1 = __half22float2(_u.h[1]);    \
        float2 _x2 = __half22float2(_u.h[2]), _x3 = __half22float2(_u.h[3]);    \
        ACC0.x = fmaf(W, _x0.x, ACC0.x); ACC0.y = fmaf(W, _x0.y, ACC0.y);       \
        ACC0.z = fmaf(W, _x1.x, ACC0.z); ACC0.w = fmaf(W, _x1.y, ACC0.w);       \
        ACC1.x = fmaf(W, _x2.x, ACC1.x); ACC1.y = fmaf(W, _x2.y, ACC1.y);       \
        ACC1.z = fmaf(W, _x3.x, ACC1.z); ACC1.w = fmaf(W, _x3.y, ACC1.w);       \
    } while (0)
#define REL_W(P) ((((P) & 3u) == 1u) ? 0.5f : ((((P) & 3u) == 2u) ? 2.0f : 1.0f))

    for (int ln = hw; ln < BS_NODES; ln += 8) {
        const int node = b * BS_NODES + ln;
        if (node >= TOTAL_NODES) break;
        vf4 a0 = {0.f, 0.f, 0.f, 0.f}, b0 = {0.f, 0.f, 0.f, 0.f};
        vf4 a1 = {0.f, 0.f, 0.f, 0.f}, b1 = {0.f, 0.f, 0.f, 0.f};
        int i = noff[ln];
        const int e1 = noff[ln + 1];
        for (; i + 8 <= e1; i += 8) {                 // 8 edges per iter, 4 loads/lane
            const unsigned int p0 = sorted[i + sub];
            const unsigned int p1 = sorted[i + 2 + sub];
            const unsigned int p2 = sorted[i + 4 + sub];
            const unsigned int p3 = sorted[i + 6 + sub];
            const float w0 = REL_W(p0), w1 = REL_W(p1), w2 = REL_W(p2), w3 = REL_W(p3);
            EDGE_FMA(p0, w0, a0, a1);
            EDGE_FMA(p1, w1, b0, b1);
            EDGE_FMA(p2, w2, a0, a1);
            EDGE_FMA(p3, w3, b0, b1);
        }
        for (; i + 2 <= e1; i += 2) {
            const unsigned int p = sorted[i + sub];
            const float w = REL_W(p);
            EDGE_FMA(p, w, a0, a1);
        }
        if (i < e1) {                                 // single leftover: sub==1 contributes 0
            const unsigned int p = sorted[i];
            const float w = sub ? 0.f : REL_W(p);
            EDGE_FMA(p, w, a0, a1);
        }
        a0 += b0; a1 += b1;
        // merge the two edge sub-streams (lane ^ 16 holds same channels)
        a0.x += __shfl_xor(a0.x, 16); a0.y += __shfl_xor(a0.y, 16);
        a0.z += __shfl_xor(a0.z, 16); a0.w += __shfl_xor(a0.w, 16);
        a1.x += __shfl_xor(a1.x, 16); a1.y += __shfl_xor(a1.y, 16);
        a1.z += __shfl_xor(a1.z, 16); a1.w += __shfl_xor(a1.w, 16);
        if (sub == 0) {
            if (MODE == 0) {
                F4H o;
                o.h[0] = __float22half2_rn({a0.x, a0.y});
                o.h[1] = __float22half2_rn({a0.z, a0.w});
                o.h[2] = __float22half2_rn({a1.x, a1.y});
                o.h[3] = __float22half2_rn({a1.z, a1.w});
                __builtin_nontemporal_store(o.f,
                    reinterpret_cast<vf4*>(reinterpret_cast<char*>(aggh) + ((size_t)node << 8) + (ch << 4)));
            } else {
                const float* ep = embf + (size_t)node * EMBED_DIM + ch * 8;
                const float4 e0 = *reinterpret_cast<const float4*>(ep);
                const float4 e1v = *reinterpret_cast<const float4*>(ep + 4);
                F4H av;
                av.f = *reinterpret_cast<const vf4*>(
                    reinterpret_cast<const char*>(xh) + ((size_t)node << 8) + (ch << 4));
                const float2 g0 = __half22float2(av.h[0]), g1 = __half22float2(av.h[1]);
                const float2 g2 = __half22float2(av.h[2]), g3 = __half22float2(av.h[3]);
                vf4 z0, z1;
                z0.x = e0.x * c1 + g0.x * c2 + a0.x * c3;
                z0.y = e0.y * c1 + g0.y * c2 + a0.y * c3;
                z0.z = e0.z * c1 + g1.x * c2 + a0.z * c3;
                z0.w = e0.w * c1 + g1.y * c2 + a0.w * c3;
                z1.x = e1v.x * c1 + g2.x * c2 + a1.x * c3;
                z1.y = e1v.y * c1 + g2.y * c2 + a1.y * c3;
                z1.z = e1v.z * c1 + g3.x * c2 + a1.z * c3;
                z1.w = e1v.w * c1 + g3.y * c2 + a1.w * c3;
                float* op = outf + (size_t)node * EMBED_DIM + ch * 8;
                __builtin_nontemporal_store(z0, reinterpret_cast<vf4*>(op));
                __builtin_nontemporal_store(z1, reinterpret_cast<vf4*>(op + 4));
            }
        }
    }
#undef EDGE_FMA
#undef REL_W
}

extern "C" void kernel_launch(void* const* d_in, const int* in_sizes, int n_in,
                              void* d_out, int out_size, void* d_ws, size_t ws_size,
                              hipStream_t stream) {
    const float* emb = (const float*)d_in[0];
    const int* s0 = (const int*)d_in[1];
    const int* d0 = (const int*)d_in[2];
    const int* s1 = (const int*)d_in[3];
    const int* d1 = (const int*)d_in[4];
    const int* s2 = (const int*)d_in[5];
    const int* d2 = (const int*)d_in[6];
    float* out = (float*)d_out;
    __half* embh = (__half*)d_out;               // d_out doubles as fp16-emb scratch

    // workspace (~93 MB)
    char* ws = (char*)d_ws;
    __half*       aggh = (__half*)ws;            ws += (size_t)N_ELEM * 2;            // 38.4 MB
    int*          gcur = (int*)ws;               ws += 64 * 4;
    int*          bcur = (int*)ws;               ws += (size_t)NBKT_PAD * 4;
    unsigned int* gbuf = (unsigned int*)ws;      ws += (size_t)NGRP * GCAP * 4;       // 26.7 MB
    unsigned int* buf2 = (unsigned int*)ws;                                           // 27.9 MB

    convert_kernel<<<2048, 256, 0, stream>>>(emb, embh, gcur, bcur);
    split1<<<3 * 512, 256, 0, stream>>>(s0, d0, s1, d1, s2, d2, gcur, gbuf);
    split2<<<NGRP * P2BLK, 256, 0, stream>>>(gcur, gbuf, bcur, buf2);

    // layer 1: aggh = raw1 (fp16)
    pull_kernel<0><<<NBKT, 256, 0, stream>>>(embh, bcur, buf2, nullptr, aggh, nullptr);
    // layer 2 + combine: out = emb/3 + raw1/9 + raw2/27
    pull_kernel<1><<<NBKT, 256, 0, stream>>>(aggh, bcur, buf2, emb, nullptr, out);
}

// Round 10
// 645.676 us; speedup vs baseline: 1.3165x; 1.0306x over previous
//
#include <hip/hip_runtime.h>
#include <hip/hip_fp16.h>

#define TOTAL_NODES 150000
#define EMBED_DIM   128
#define NUM_EDGES   2000000
#define N_ELEM      (TOTAL_NODES * EMBED_DIM)   // 19,200,000

#define NGRP     37          // coarse groups of 4096 nodes (src>>12)
#define GCAP     180224      // words per group region (44*4096)
#define EPB      8192        // edges per block in split kernels (512 thr x 16)
#define S1BLK    256         // blocks per relation in split1 (244 active + tail)
#define NBKT     2344        // buckets of 64 nodes (src>>6)
#define NBKT_PAD 2368        // 37*64
#define SCAP2    2944        // per-bucket capacity (mean 2560, +7.5 sigma)
#define P2BLK    22          // split2 blocks per group (22*8192 >= GCAP)
#define BS_NODES 64

typedef float vf2 __attribute__((ext_vector_type(2)));
typedef float vf4 __attribute__((ext_vector_type(4)));

// fp32 -> fp16 table (embh lives in d_out scratch) + cursor zeroing
__global__ void convert_kernel(const float* __restrict__ in, __half* __restrict__ outh,
                               int* __restrict__ gcur, int* __restrict__ bcur) {
    const int n4 = N_ELEM / 4;
    const int stride = gridDim.x * blockDim.x;
    const int gid = blockIdx.x * blockDim.x + threadIdx.x;
    if (gid < NGRP) gcur[gid] = 0;
    if (gid < NBKT_PAD) bcur[gid] = 0;
    for (int i = gid; i < n4; i += stride) {
        float4 v = reinterpret_cast<const float4*>(in)[i];
        union { __half2 h[2]; vf2 f; } u;
        u.h[0] = __float22half2_rn({v.x, v.y});
        u.h[1] = __float22half2_rn({v.z, v.w});
        __builtin_nontemporal_store(u.f, reinterpret_cast<vf2*>(outh) + i);
    }
}

// pass 1: bin 6M edges into 37 coarse groups, contiguous coalesced runs per block
__global__ __launch_bounds__(512) void split1(const int* __restrict__ s0, const int* __restrict__ d0,
                                              const int* __restrict__ s1, const int* __restrict__ d1,
                                              const int* __restrict__ s2, const int* __restrict__ d2,
                                              int* __restrict__ gcur, unsigned int* __restrict__ gbuf) {
    const int rel   = blockIdx.x >> 8;               // S1BLK=256 blocks per relation
    const int inner = blockIdx.x & (S1BLK - 1);
    const int base  = inner * EPB;
    const int ne    = min(EPB, NUM_EDGES - base);    // tail ne=1152, multiple of 4
    if (ne <= 0) return;
    const int* sp = (rel == 0) ? s0 : ((rel == 1) ? s1 : s2);
    const int* dp = (rel == 0) ? d0 : ((rel == 1) ? d1 : d2);

    __shared__ int cnt[NGRP], excl[NGRP], bas[NGRP], rc[NGRP];
    __shared__ unsigned int stage[EPB];
    __shared__ unsigned char grp[EPB];
    const int t = threadIdx.x;
    if (t < NGRP) cnt[t] = 0;
    __syncthreads();

    unsigned int pay[16];
    int pg[16];
    #pragma unroll
    for (int q = 0; q < 4; ++q) {
        const int idx = (q * 512 + t) * 4;
        if (idx < ne) {
            const int4 s4 = *reinterpret_cast<const int4*>(sp + base + idx);
            const int4 d4 = *reinterpret_cast<const int4*>(dp + base + idx);
            const int ss[4] = {s4.x, s4.y, s4.z, s4.w};
            const int dd[4] = {d4.x, d4.y, d4.z, d4.w};
            #pragma unroll
            for (int k = 0; k < 4; ++k) {
                const int g = ss[k] >> 12;
                pay[q * 4 + k] = ((unsigned int)(ss[k] & 4095) << 20) |
                                 ((unsigned int)dd[k] << 2) | (unsigned int)rel;
                pg[q * 4 + k] = g;
                atomicAdd(&cnt[g], 1);
            }
        }
    }
    __syncthreads();
    if (t == 0) { int run = 0; for (int i = 0; i < NGRP; ++i) { excl[i] = run; run += cnt[i]; } }
    __syncthreads();
    if (t < NGRP) { if (cnt[t] > 0) bas[t] = atomicAdd(&gcur[t], cnt[t]); rc[t] = excl[t]; }
    __syncthreads();
    #pragma unroll
    for (int q = 0; q < 4; ++q) {
        const int idx = (q * 512 + t) * 4;
        if (idx < ne) {
            #pragma unroll
            for (int k = 0; k < 4; ++k) {
                const int g = pg[q * 4 + k];
                const int pos = atomicAdd(&rc[g], 1);
                stage[pos] = pay[q * 4 + k];
                grp[pos] = (unsigned char)g;
            }
        }
    }
    __syncthreads();
    for (int j = t; j < ne; j += 512) {
        const int g = grp[j];
        const int o = bas[g] + (j - excl[g]);
        if (o < GCAP) gbuf[(size_t)g * GCAP + o] = stage[j];
    }
}

// pass 2: split each group into its 64 buckets (contiguous bucket regions)
__global__ __launch_bounds__(512) void split2(const int* __restrict__ gcur,
                                              const unsigned int* __restrict__ gbuf,
                                              int* __restrict__ bcur, unsigned int* __restrict__ buf2) {
    const int g     = blockIdx.x / P2BLK;
    const int inner = blockIdx.x % P2BLK;
    const int gsz   = min(gcur[g], GCAP);
    const int base  = inner * EPB;
    if (base >= gsz) return;
    const int ne = min(EPB, gsz - base);
    const unsigned int* src = gbuf + (size_t)g * GCAP + base;

    __shared__ int cnt[64], excl[64], bas2[64], rc[64];
    __shared__ unsigned int stage[EPB];
    const int t = threadIdx.x;
    if (t < 64) cnt[t] = 0;
    __syncthreads();

    unsigned int pay[16];
    #pragma unroll
    for (int q = 0; q < 4; ++q) {
        const int idx = (q * 512 + t) * 4;
        if (idx + 4 <= ne) {
            const uint4 v = *reinterpret_cast<const uint4*>(src + idx);
            pay[q * 4 + 0] = v.x; pay[q * 4 + 1] = v.y;
            pay[q * 4 + 2] = v.z; pay[q * 4 + 3] = v.w;
            atomicAdd(&cnt[(v.x >> 26) & 63], 1);
            atomicAdd(&cnt[(v.y >> 26) & 63], 1);
            atomicAdd(&cnt[(v.z >> 26) & 63], 1);
            atomicAdd(&cnt[(v.w >> 26) & 63], 1);
        } else {
            #pragma unroll
            for (int k = 0; k < 4; ++k) {
                if (idx + k < ne) {
                    const unsigned int p = src[idx + k];
                    pay[q * 4 + k] = p;
                    atomicAdd(&cnt[(p >> 26) & 63], 1);
                }
            }
        }
    }
    __syncthreads();
    if (t == 0) { int run = 0; for (int i = 0; i < 64; ++i) { excl[i] = run; run += cnt[i]; } }
    __syncthreads();
    if (t < 64) { if (cnt[t] > 0) bas2[t] = atomicAdd(&bcur[g * 64 + t], cnt[t]); rc[t] = excl[t]; }
    __syncthreads();
    #pragma unroll
    for (int q = 0; q < 4; ++q) {
        const int idx = (q * 512 + t) * 4;
        #pragma unroll
        for (int k = 0; k < 4; ++k) {
            if (idx + k < ne) {
                const unsigned int p = pay[q * 4 + k];
                const int pos = atomicAdd(&rc[(p >> 26) & 63], 1);
                stage[pos] = p;
            }
        }
    }
    __syncthreads();
    for (int j = t; j < ne; j += 512) {
        const unsigned int p = stage[j];
        const int bb = (p >> 26) & 63;
        const int o = bas2[bb] + (j - excl[bb]);
        if (o < SCAP2) buf2[(size_t)(g * 64 + bb) * SCAP2 + o] = p;
    }
}

// pull: per-bucket LDS counting sort + 8B/lane fp16 gather, 8x unrolled (R7 inner loop)
// MODE 0: aggh[n] = raw1 (fp16)
// MODE 1: out[n]  = embf[n]/3 + aggh_row/9 + raw2/27 (fp32)
template <int MODE>
__global__ __launch_bounds__(256) void pull_kernel(const __half* __restrict__ xh,
                                                   const int* __restrict__ bcur,
                                                   const unsigned int* __restrict__ buf2,
                                                   const float* __restrict__ embf,
                                                   __half* __restrict__ aggh,
                                                   float* __restrict__ outf) {
    __shared__ unsigned int sorted[SCAP2];
    __shared__ int cnt[64], cur[64], noff[65];
    const int b = blockIdx.x, t = threadIdx.x;
    const int c = min(bcur[b], SCAP2);
    const unsigned int* rb = buf2 + (size_t)b * SCAP2;
    if (t < 64) cnt[t] = 0;
    __syncthreads();
    for (int i = t; i < c; i += 256) atomicAdd(&cnt[(rb[i] >> 20) & 63], 1);
    __syncthreads();
    if (t == 0) { int run = 0; for (int i = 0; i < 64; ++i) { noff[i] = run; run += cnt[i]; } noff[64] = run; }
    __syncthreads();
    if (t < 64) cur[t] = noff[t];
    __syncthreads();
    for (int i = t; i < c; i += 256) {
        const unsigned int p = rb[i];
        const int pos = atomicAdd(&cur[(p >> 20) & 63], 1);
        sorted[pos] = p & 0xFFFFFu;                   // (dst<<2)|rel
    }
    __syncthreads();

    const int hw = t >> 5, lane = t & 31;
    const char* xb = reinterpret_cast<const char*>(xh) + (lane << 3);
    union F2H { vf2 f; __half2 h[2]; };
#define REL_W(P) ((((P) & 3u) == 1u) ? 0.5f : ((((P) & 3u) == 2u) ? 2.0f : 1.0f))
    for (int ln = hw; ln < BS_NODES; ln += 8) {
        const int node = b * BS_NODES + ln;
        if (node >= TOTAL_NODES) break;
        vf4 acc0 = {0.f, 0.f, 0.f, 0.f};
        vf4 acc1 = {0.f, 0.f, 0.f, 0.f};
        int i = noff[ln];
        const int e1 = noff[ln + 1];
        for (; i + 8 <= e1; i += 8) {
            const unsigned int p0 = sorted[i + 0], p1 = sorted[i + 1];
            const unsigned int p2 = sorted[i + 2], p3 = sorted[i + 3];
            const unsigned int p4 = sorted[i + 4], p5 = sorted[i + 5];
            const unsigned int p6 = sorted[i + 6], p7 = sorted[i + 7];
            F2H u0, u1, u2, u3, u4, u5, u6, u7;
            u0.f = *reinterpret_cast<const vf2*>(xb + ((size_t)(p0 >> 2) << 8));
            u1.f = *reinterpret_cast<const vf2*>(xb + ((size_t)(p1 >> 2) << 8));
            u2.f = *reinterpret_cast<const vf2*>(xb + ((size_t)(p2 >> 2) << 8));
            u3.f = *reinterpret_cast<const vf2*>(xb + ((size_t)(p3 >> 2) << 8));
            u4.f = *reinterpret_cast<const vf2*>(xb + ((size_t)(p4 >> 2) << 8));
            u5.f = *reinterpret_cast<const vf2*>(xb + ((size_t)(p5 >> 2) << 8));
            u6.f = *reinterpret_cast<const vf2*>(xb + ((size_t)(p6 >> 2) << 8));
            u7.f = *reinterpret_cast<const vf2*>(xb + ((size_t)(p7 >> 2) << 8));
            const float w0 = REL_W(p0), w1 = REL_W(p1), w2 = REL_W(p2), w3 = REL_W(p3);
            const float w4 = REL_W(p4), w5 = REL_W(p5), w6 = REL_W(p6), w7 = REL_W(p7);
            float2 f0a = __half22float2(u0.h[0]), f0b = __half22float2(u0.h[1]);
            float2 f1a = __half22float2(u1.h[0]), f1b = __half22float2(u1.h[1]);
            float2 f2a = __half22float2(u2.h[0]), f2b = __half22float2(u2.h[1]);
            float2 f3a = __half22float2(u3.h[0]), f3b = __half22float2(u3.h[1]);
            float2 f4a = __half22float2(u4.h[0]), f4b = __half22float2(u4.h[1]);
            float2 f5a = __half22float2(u5.h[0]), f5b = __half22float2(u5.h[1]);
            float2 f6a = __half22float2(u6.h[0]), f6b = __half22float2(u6.h[1]);
            float2 f7a = __half22float2(u7.h[0]), f7b = __half22float2(u7.h[1]);
            acc0.x = fmaf(w0, f0a.x, acc0.x); acc0.y = fmaf(w0, f0a.y, acc0.y);
            acc0.z = fmaf(w0, f0b.x, acc0.z); acc0.w = fmaf(w0, f0b.y, acc0.w);
            acc1.x = fmaf(w1, f1a.x, acc1.x); acc1.y = fmaf(w1, f1a.y, acc1.y);
            acc1.z = fmaf(w1, f1b.x, acc1.z); acc1.w = fmaf(w1, f1b.y, acc1.w);
            acc0.x = fmaf(w2, f2a.x, acc0.x); acc0.y = fmaf(w2, f2a.y, acc0.y);
            acc0.z = fmaf(w2, f2b.x, acc0.z); acc0.w = fmaf(w2, f2b.y, acc0.w);
            acc1.x = fmaf(w3, f3a.x, acc1.x); acc1.y = fmaf(w3, f3a.y, acc1.y);
            acc1.z = fmaf(w3, f3b.x, acc1.z); acc1.w = fmaf(w3, f3b.y, acc1.w);
            acc0.x = fmaf(w4, f4a.x, acc0.x); acc0.y = fmaf(w4, f4a.y, acc0.y);
            acc0.z = fmaf(w4, f4b.x, acc0.z); acc0.w = fmaf(w4, f4b.y, acc0.w);
            acc1.x = fmaf(w5, f5a.x, acc1.x); acc1.y = fmaf(w5, f5a.y, acc1.y);
            acc1.z = fmaf(w5, f5b.x, acc1.z); acc1.w = fmaf(w5, f5b.y, acc1.w);
            acc0.x = fmaf(w6, f6a.x, acc0.x); acc0.y = fmaf(w6, f6a.y, acc0.y);
            acc0.z = fmaf(w6, f6b.x, acc0.z); acc0.w = fmaf(w6, f6b.y, acc0.w);
            acc1.x = fmaf(w7, f7a.x, acc1.x); acc1.y = fmaf(w7, f7a.y, acc1.y);
            acc1.z = fmaf(w7, f7b.x, acc1.z); acc1.w = fmaf(w7, f7b.y, acc1.w);
        }
        for (; i < e1; ++i) {
            const unsigned int p = sorted[i];
            const float w = REL_W(p);
            F2H u;
            u.f = *reinterpret_cast<const vf2*>(xb + ((size_t)(p >> 2) << 8));
            float2 fa = __half22float2(u.h[0]), fb = __half22float2(u.h[1]);
            acc0.x = fmaf(w, fa.x, acc0.x); acc0.y = fmaf(w, fa.y, acc0.y);
            acc0.z = fmaf(w, fb.x, acc0.z); acc0.w = fmaf(w, fb.y, acc0.w);
        }
        vf4 acc = acc0 + acc1;
        if (MODE == 0) {
            F2H o;
            o.h[0] = __float22half2_rn({acc.x, acc.y});
            o.h[1] = __float22half2_rn({acc.z, acc.w});
            __builtin_nontemporal_store(o.f,
                reinterpret_cast<vf2*>(reinterpret_cast<char*>(aggh) + (((size_t)node) << 8) + (lane << 3)));
        } else {
            const float4 e = *reinterpret_cast<const float4*>(embf + (size_t)node * EMBED_DIM + lane * 4);
            F2H a;
            a.f = *reinterpret_cast<const vf2*>(
                reinterpret_cast<const char*>(xh) + (((size_t)node) << 8) + (lane << 3));
            float2 a0 = __half22float2(a.h[0]);
            float2 a1 = __half22float2(a.h[1]);
            const float c1 = 1.f / 3.f, c2 = 1.f / 9.f, c3 = 1.f / 27.f;
            vf4 z;
            z.x = e.x * c1 + a0.x * c2 + acc.x * c3;
            z.y = e.y * c1 + a0.y * c2 + acc.y * c3;
            z.z = e.z * c1 + a1.x * c2 + acc.z * c3;
            z.w = e.w * c1 + a1.y * c2 + acc.w * c3;
            __builtin_nontemporal_store(z,
                reinterpret_cast<vf4*>(outf + (size_t)node * EMBED_DIM + lane * 4));
        }
    }
#undef REL_W
}

extern "C" void kernel_launch(void* const* d_in, const int* in_sizes, int n_in,
                              void* d_out, int out_size, void* d_ws, size_t ws_size,
                              hipStream_t stream) {
    const float* emb = (const float*)d_in[0];
    const int* s0 = (const int*)d_in[1];
    const int* d0 = (const int*)d_in[2];
    const int* s1 = (const int*)d_in[3];
    const int* d1 = (const int*)d_in[4];
    const int* s2 = (const int*)d_in[5];
    const int* d2 = (const int*)d_in[6];
    float* out = (float*)d_out;
    __half* embh = (__half*)d_out;               // d_out doubles as fp16-emb scratch

    // workspace (~93 MB)
    char* ws = (char*)d_ws;
    __half*       aggh = (__half*)ws;            ws += (size_t)N_ELEM * 2;            // 38.4 MB
    int*          gcur = (int*)ws;               ws += 64 * 4;
    int*          bcur = (int*)ws;               ws += (size_t)NBKT_PAD * 4;
    unsigned int* gbuf = (unsigned int*)ws;      ws += (size_t)NGRP * GCAP * 4;       // 26.7 MB
    unsigned int* buf2 = (unsigned int*)ws;                                           // 27.9 MB

    convert_kernel<<<2048, 256, 0, stream>>>(emb, embh, gcur, bcur);
    split1<<<3 * S1BLK, 512, 0, stream>>>(s0, d0, s1, d1, s2, d2, gcur, gbuf);
    split2<<<NGRP * P2BLK, 512, 0, stream>>>(gcur, gbuf, bcur, buf2);

    // layer 1: aggh = raw1 (fp16)
    pull_kernel<0><<<NBKT, 256, 0, stream>>>(embh, bcur, buf2, nullptr, aggh, nullptr);
    // layer 2 + combine: out = emb/3 + raw1/9 + raw2/27
    pull_kernel<1><<<NBKT, 256, 0, stream>>>(aggh, bcur, buf2, emb, nullptr, out);
}